// Round 1
// baseline (264.487 us; speedup 1.0000x reference)
//
#include <hip/hip_runtime.h>
#include <stdint.h>
#include <stddef.h>

typedef unsigned short u16;
typedef unsigned int u32;
typedef float f32x4 __attribute__((ext_vector_type(4)));
typedef __bf16 bf16x8 __attribute__((ext_vector_type(8)));
typedef uint32_t u32x4 __attribute__((ext_vector_type(4)));
typedef uint32_t u32x2 __attribute__((ext_vector_type(2)));

#define DEVINL static __device__ __forceinline__

DEVINL u16 f2bf(float f) {
  union { float f; u32 u; } x; x.f = f;
  u32 r = (x.u + 0x7fffu + ((x.u >> 16) & 1u)) >> 16;
  return (u16)r;
}
DEVINL float bflo(u32 x) { union { u32 u; float f; } t; t.u = x << 16; return t.f; }
DEVINL float bfhi(u32 x) { union { u32 u; float f; } t; t.u = x & 0xffff0000u; return t.f; }

DEVINL void gl_lds16(const u16* g, u16* l) {
  __builtin_amdgcn_global_load_lds(
      (const __attribute__((address_space(1))) u32*)(const void*)g,
      (__attribute__((address_space(3))) u32*)(void*)l, 16, 0, 0);
}

DEVINL f32x4 mfma16(bf16x8 a, bf16x8 b, f32x4 c) {
  return __builtin_amdgcn_mfma_f32_16x16x32_bf16(a, b, c, 0, 0, 0);
}

// ---------------- f32 -> bf16 convert (vectorized) ----------------
__global__ void k_cvt(const float* __restrict__ src, u16* __restrict__ dst, int n4) {
  int i = blockIdx.x * 256 + threadIdx.x;
  if (i >= n4) return;
  f32x4 v = ((const f32x4*)src)[i];
  u32x2 o;
  o[0] = (u32)f2bf(v[0]) | ((u32)f2bf(v[1]) << 16);
  o[1] = (u32)f2bf(v[2]) | ((u32)f2bf(v[3]) << 16);
  ((u32x2*)dst)[i] = o;
}

// ---------------- transpose + convert: src(R x C) f32 -> dst(C x R) bf16 ----------------
__global__ void k_tcvt(const float* __restrict__ src, u16* __restrict__ dst, int R, int C) {
  __shared__ float tile[32][33];
  int tx = threadIdx.x, ty = threadIdx.y;
  int c0 = blockIdx.x * 32, r0 = blockIdx.y * 32;
#pragma unroll
  for (int j = ty; j < 32; j += 8)
    tile[j][tx] = src[(size_t)(r0 + j) * C + (c0 + tx)];
  __syncthreads();
#pragma unroll
  for (int j = ty; j < 32; j += 8)
    dst[(size_t)(c0 + j) * R + (r0 + tx)] = f2bf(tile[tx][j]);
}

// ---------------- bf16 GEMM: C(MxN) = A(MxK) * Bt(NxK)^T + bias ----------------
// MODE 1: out bf16, 3-piece bias (QKV).  MODE 2: out f32, bias b0, N-tail guarded.
template <int MODE>
__global__ __launch_bounds__(256, 2) void k_gemm(
    const u16* __restrict__ A, const u16* __restrict__ B, void* __restrict__ Cout,
    const float* __restrict__ b0, const float* __restrict__ b1, const float* __restrict__ b2,
    int M, int N, int K, int ldc)
{
  __shared__ u16 Al[128 * 64];
  __shared__ u16 Bl[128 * 64];
  const int tid = threadIdx.x;
  const int w = tid >> 6, lane = tid & 63;
  const int l15 = lane & 15, lg = lane >> 4;
  const int m0 = blockIdx.y * 128, n0 = blockIdx.x * 128;
  const int wr = w >> 1, wc = w & 1;
  const int lrow = lane >> 3, lcol = lane & 7;

  f32x4 acc[4][4] = {};

  for (int kt = 0; kt < K; kt += 64) {
    if (kt) __syncthreads();
#pragma unroll
    for (int i = 0; i < 4; ++i) {
      int ar = m0 + i * 32 + w * 8 + lrow;
      gl_lds16(A + (size_t)ar * K + kt + lcol * 8, &Al[(i * 32 + w * 8) * 64]);
      int br = n0 + i * 32 + w * 8 + lrow;
      if (br >= N) br = N - 1;
      gl_lds16(B + (size_t)br * K + kt + lcol * 8, &Bl[(i * 32 + w * 8) * 64]);
    }
    __syncthreads();
#pragma unroll
    for (int ks = 0; ks < 2; ++ks) {
      bf16x8 af[4], bfr[4];
#pragma unroll
      for (int mt = 0; mt < 4; ++mt)
        af[mt] = *(const bf16x8*)&Al[(wr * 64 + mt * 16 + l15) * 64 + ks * 32 + lg * 8];
#pragma unroll
      for (int nt = 0; nt < 4; ++nt)
        bfr[nt] = *(const bf16x8*)&Bl[(wc * 64 + nt * 16 + l15) * 64 + ks * 32 + lg * 8];
#pragma unroll
      for (int mt = 0; mt < 4; ++mt)
#pragma unroll
        for (int nt = 0; nt < 4; ++nt)
          acc[mt][nt] = mfma16(af[mt], bfr[nt], acc[mt][nt]);
    }
  }

#pragma unroll
  for (int mt = 0; mt < 4; ++mt)
#pragma unroll
    for (int nt = 0; nt < 4; ++nt) {
      int col = n0 + wc * 64 + nt * 16 + l15;
      if (MODE == 2 && col >= N) continue;
      float bias = (MODE == 1)
          ? ((col < 4096) ? b0[col] : (col < 4608) ? b1[col - 4096] : b2[col - 4608])
          : b0[col];
#pragma unroll
      for (int r = 0; r < 4; ++r) {
        int row = m0 + wr * 64 + mt * 16 + lg * 4 + r;
        float v = acc[mt][nt][r] + bias;
        if (MODE == 1) ((u16*)Cout)[(size_t)row * ldc + col] = f2bf(v);
        else ((float*)Cout)[(size_t)row * ldc + col] = v;
      }
    }
}

// ---------------- in-place RoPE on QKV cols [0, 4608) ----------------
__global__ void k_rope(u16* __restrict__ qkv, const float* __restrict__ cosb,
                       const float* __restrict__ sinb) {
  int idx = blockIdx.x * 256 + threadIdx.x;  // S * 72 * 4 = 589824
  if (idx >= 2048 * 72 * 4) return;
  int oct = idx & 3;
  int h = (idx >> 2) % 72;
  int s = idx / 288;
  u16* p1 = qkv + (size_t)s * 5120 + h * 64 + oct * 8;  // dims d0..d0+7  (first half)
  u16* p2 = p1 + 32;                                    // dims d0+32..   (second half)
  const float* pc = cosb + (size_t)s * 64 + oct * 8;
  const float* ps = sinb + (size_t)s * 64 + oct * 8;
  u32x4 a = *(const u32x4*)p1;
  u32x4 b = *(const u32x4*)p2;
  f32x4 c0 = *(const f32x4*)pc, c1 = *(const f32x4*)(pc + 4);
  f32x4 s0 = *(const f32x4*)ps, s1 = *(const f32x4*)(ps + 4);
  float C[8] = {c0[0], c0[1], c0[2], c0[3], c1[0], c1[1], c1[2], c1[3]};
  float Sn[8] = {s0[0], s0[1], s0[2], s0[3], s1[0], s1[1], s1[2], s1[3]};
  u32x4 ra, rb;
#pragma unroll
  for (int i = 0; i < 4; ++i) {
    float x1l = bflo(a[i]), x1h = bfhi(a[i]);
    float x2l = bflo(b[i]), x2h = bfhi(b[i]);
    float o1l = x1l * C[2 * i] - x2l * Sn[2 * i];
    float o1h = x1h * C[2 * i + 1] - x2h * Sn[2 * i + 1];
    float o2l = x2l * C[2 * i] + x1l * Sn[2 * i];
    float o2h = x2h * C[2 * i + 1] + x1h * Sn[2 * i + 1];
    ra[i] = (u32)f2bf(o1l) | ((u32)f2bf(o1h) << 16);
    rb[i] = (u32)f2bf(o2l) | ((u32)f2bf(o2h) << 16);
  }
  *(u32x4*)p1 = ra;
  *(u32x4*)p2 = rb;
}

// ---------------- sliding-window GQA attention with sinks ----------------
// grid: (S/32, NKV), block 512 (8 waves = 8 q-heads of this kv head)
__global__ __launch_bounds__(512, 1) void k_attn(
    const u16* __restrict__ qkv, const float* __restrict__ sinks, u16* __restrict__ aout)
{
  __shared__ u16 Kl[160 * 64];          // XOR-swizzled rows
  __shared__ u16 Vt[64 * 168];          // V transposed [dim][key], pad 8
  __shared__ u16 Pl[8][2][16][40];      // per-wave P transpose buffer

  const int qt = blockIdx.x * 32;
  const int kv = blockIdx.y;
  const int tid = threadIdx.x;
  const int w = tid >> 6, lane = tid & 63;
  const int l15 = lane & 15, lg = lane >> 4;

  // stage K (swizzled) and V (transposed); keys qt-128 .. qt+31
  for (int idx = tid; idx < 160 * 8; idx += 512) {
    int row = idx >> 3, ch = idx & 7;
    int key = qt - 128 + row;
    u32x4 val = {0, 0, 0, 0};
    if (key >= 0) val = *(const u32x4*)(qkv + (size_t)key * 5120 + 4096 + kv * 64 + ch * 8);
    *(u32x4*)((char*)Kl + row * 128 + ((ch * 16) ^ ((row & 7) << 4))) = val;
  }
  for (int idx = tid; idx < 160 * 8; idx += 512) {
    int row = idx >> 3, ch = idx & 7;
    int key = qt - 128 + row;
    u32x4 val = {0, 0, 0, 0};
    if (key >= 0) val = *(const u32x4*)(qkv + (size_t)key * 5120 + 4608 + kv * 64 + ch * 8);
    const u16* pv16 = (const u16*)&val;
#pragma unroll
    for (int j = 0; j < 8; ++j) Vt[(ch * 8 + j) * 168 + row] = pv16[j];
  }
  __syncthreads();

  const int h = kv * 8 + w;
  const float sink = sinks[h];

  bf16x8 qf[2][2];
#pragma unroll
  for (int rt = 0; rt < 2; ++rt)
#pragma unroll
    for (int ks = 0; ks < 2; ++ks)
      qf[rt][ks] = *(const bf16x8*)(qkv + (size_t)(qt + rt * 16 + l15) * 5120 + h * 64 + ks * 32 + lg * 8);

  // scores: S[rt][kb][hh] 16x16 frags; D[row=q][col=key]
  f32x4 S[2][5][2];
#pragma unroll
  for (int kb = 0; kb < 5; ++kb)
#pragma unroll
    for (int hh = 0; hh < 2; ++hh) {
      int krow = kb * 32 + hh * 16 + l15;
      int sw = (krow & 7) << 4;
      bf16x8 kf0 = *(const bf16x8*)((const char*)Kl + krow * 128 + ((lg * 16) ^ sw));
      bf16x8 kf1 = *(const bf16x8*)((const char*)Kl + krow * 128 + ((64 + lg * 16) ^ sw));
#pragma unroll
      for (int rt = 0; rt < 2; ++rt) {
        f32x4 a = {0.f, 0.f, 0.f, 0.f};
        a = mfma16(qf[rt][0], kf0, a);
        a = mfma16(qf[rt][1], kf1, a);
        S[rt][kb][hh] = a;
      }
    }

  // mask + softmax (sink in max & denom)
  float inv_s[2][4];
#pragma unroll
  for (int rt = 0; rt < 2; ++rt)
#pragma unroll
    for (int r = 0; r < 4; ++r) {
      int q_abs = qt + rt * 16 + lg * 4 + r;
      float m = -1e30f;
#pragma unroll
      for (int kb = 0; kb < 5; ++kb)
#pragma unroll
        for (int hh = 0; hh < 2; ++hh) {
          int k_abs = qt - 128 + kb * 32 + hh * 16 + l15;
          float v = S[rt][kb][hh][r] * 0.125f;
          bool ok = (k_abs >= 0) && (k_abs <= q_abs) && (q_abs - k_abs < 128);
          v = ok ? v : -1e30f;
          S[rt][kb][hh][r] = v;
          m = fmaxf(m, v);
        }
      m = fmaxf(m, __shfl_xor(m, 1, 64));
      m = fmaxf(m, __shfl_xor(m, 2, 64));
      m = fmaxf(m, __shfl_xor(m, 4, 64));
      m = fmaxf(m, __shfl_xor(m, 8, 64));
      m = fmaxf(m, sink);
      float sum = 0.f;
#pragma unroll
      for (int kb = 0; kb < 5; ++kb)
#pragma unroll
        for (int hh = 0; hh < 2; ++hh) {
          float p = __expf(S[rt][kb][hh][r] - m);
          S[rt][kb][hh][r] = p;
          sum += p;
        }
      sum += __shfl_xor(sum, 1, 64);
      sum += __shfl_xor(sum, 2, 64);
      sum += __shfl_xor(sum, 4, 64);
      sum += __shfl_xor(sum, 8, 64);
      inv_s[rt][r] = 1.0f / (sum + __expf(sink - m));
    }

  // PV: transpose P via per-wave LDS, MFMA against Vt
  f32x4 pv[2][4] = {};
#pragma unroll
  for (int kb = 0; kb < 5; ++kb) {
    asm volatile("s_waitcnt lgkmcnt(0)" ::: "memory");
#pragma unroll
    for (int rt = 0; rt < 2; ++rt)
#pragma unroll
      for (int hh = 0; hh < 2; ++hh)
#pragma unroll
        for (int r = 0; r < 4; ++r)
          Pl[w][rt][lg * 4 + r][hh * 16 + l15] = f2bf(S[rt][kb][hh][r] * inv_s[rt][r]);
    asm volatile("s_waitcnt lgkmcnt(0)" ::: "memory");
    __builtin_amdgcn_sched_barrier(0);
    bf16x8 a0 = *(const bf16x8*)&Pl[w][0][l15][lg * 8];
    bf16x8 a1 = *(const bf16x8*)&Pl[w][1][l15][lg * 8];
#pragma unroll
    for (int nt = 0; nt < 4; ++nt) {
      bf16x8 vf = *(const bf16x8*)&Vt[(nt * 16 + l15) * 168 + kb * 32 + lg * 8];
      pv[0][nt] = mfma16(a0, vf, pv[0][nt]);
      pv[1][nt] = mfma16(a1, vf, pv[1][nt]);
    }
  }

#pragma unroll
  for (int rt = 0; rt < 2; ++rt)
#pragma unroll
    for (int nt = 0; nt < 4; ++nt)
#pragma unroll
      for (int r = 0; r < 4; ++r)
        aout[(size_t)(qt + rt * 16 + lg * 4 + r) * 4096 + h * 64 + nt * 16 + l15] =
            f2bf(pv[rt][nt][r]);
}

extern "C" void kernel_launch(void* const* d_in, const int* in_sizes, int n_in,
                              void* d_out, int out_size, void* d_ws, size_t ws_size,
                              hipStream_t stream) {
  const float* hs    = (const float*)d_in[0];
  const float* cosb  = (const float*)d_in[1];
  const float* sinb  = (const float*)d_in[2];
  const float* Wq    = (const float*)d_in[3];
  const float* bq    = (const float*)d_in[4];
  const float* Wk    = (const float*)d_in[5];
  const float* bk    = (const float*)d_in[6];
  const float* Wv    = (const float*)d_in[7];
  const float* bv    = (const float*)d_in[8];
  const float* Wo    = (const float*)d_in[9];
  const float* bo    = (const float*)d_in[10];
  const float* sinks = (const float*)d_in[11];

  char* ws = (char*)d_ws;
  u16* hsb   = (u16*)ws;  ws += (size_t)2048 * 2880 * 2;
  u16* WqkvT = (u16*)ws;  ws += (size_t)5120 * 2880 * 2;
  u16* WoT   = (u16*)ws;  ws += (size_t)2880 * 4096 * 2;
  u16* QKV   = (u16*)ws;  ws += (size_t)2048 * 5120 * 2;
  u16* AOut  = (u16*)ws;  ws += (size_t)2048 * 4096 * 2;

  dim3 tblk(32, 8);
  k_cvt<<<5760, 256, 0, stream>>>(hs, hsb, 1474560);
  k_tcvt<<<dim3(4096 / 32, 2880 / 32), tblk, 0, stream>>>(Wq, WqkvT, 2880, 4096);
  k_tcvt<<<dim3(512 / 32, 2880 / 32), tblk, 0, stream>>>(Wk, WqkvT + (size_t)4096 * 2880, 2880, 512);
  k_tcvt<<<dim3(512 / 32, 2880 / 32), tblk, 0, stream>>>(Wv, WqkvT + (size_t)4608 * 2880, 2880, 512);
  k_tcvt<<<dim3(2880 / 32, 4096 / 32), tblk, 0, stream>>>(Wo, WoT, 4096, 2880);

  k_gemm<1><<<dim3(5120 / 128, 2048 / 128), 256, 0, stream>>>(
      hsb, WqkvT, QKV, bq, bk, bv, 2048, 5120, 2880, 5120);

  k_rope<<<2304, 256, 0, stream>>>(QKV, cosb, sinb);

  k_attn<<<dim3(64, 8), 512, 0, stream>>>(QKV, sinks, AOut);

  k_gemm<2><<<dim3((2880 + 127) / 128, 2048 / 128), 256, 0, stream>>>(
      AOut, WoT, d_out, bo, nullptr, nullptr, 2048, 2880, 4096, 2880);
}